// Round 6
// baseline (12189.767 us; speedup 1.0000x reference)
//
#include <hip/hip_runtime.h>
#include <hip/hip_bf16.h>

typedef __attribute__((ext_vector_type(8))) short bf16x8;      // 8 bf16 = 4 VGPRs (MFMA A/B frag)
typedef __attribute__((ext_vector_type(4))) short short4v;     // 4 bf16
typedef __attribute__((ext_vector_type(4))) float f32x4;       // MFMA C/D frag

#define N_IN  60000
#define N_OUT 160000
#define C     128
#define EPS   1e-3f
#define SLOPE 0.01f
#define LDSP  132    // LDS accumulator row pitch (dwords): 132%32=4 -> 2-way bank pattern (free)

__device__ inline short f2bf(float f) {            // RNE f32 -> bf16
    unsigned u = __builtin_bit_cast(unsigned, f);
    u += 0x7FFFu + ((u >> 16) & 1u);
    return (short)(u >> 16);
}
__device__ inline float lrelu(float x) { return x > 0.f ? x : SLOPE * x; }

// ---------------- f32 -> bf16 convert ----------------
__global__ __launch_bounds__(256) void k_f32_to_bf16(const float* __restrict__ in,
                                                     short* __restrict__ out, int count4) {
    int i = blockIdx.x * 256 + threadIdx.x, stride = gridDim.x * 256;
    for (; i < count4; i += stride) {
        f32x4 v = ((const f32x4*)in)[i];
        short4v o;
        o.x = f2bf(v.x); o.y = f2bf(v.y); o.z = f2bf(v.z); o.w = f2bf(v.w);
        ((short4v*)out)[i] = o;
    }
}

// ---------------- W (f32 [K][128][128]) -> bf16 fragment-layout buffer ----------------
// fragid bits: [kk:2][lhi:2][w:2][n:1][l15:4]  (2048 frags/tap, 16B each = 32KB = W[k])
// Element j of frag = W[k][kk*32+lhi*8+j][w*32+n*16+l15].
__global__ __launch_bounds__(256) void k_wconv(const float* __restrict__ W,
                                               short* __restrict__ Wb, int K) {
    int tid = blockIdx.x * 256 + threadIdx.x;
    if (tid >= K * 2048) return;
    int idx = tid;
    int l15 = idx & 15;  idx >>= 4;
    int n   = idx & 1;   idx >>= 1;
    int w   = idx & 3;   idx >>= 2;
    int lhi = idx & 3;   idx >>= 2;
    int kk  = idx & 3;   idx >>= 2;
    int k   = idx;
    int col = w * 32 + n * 16 + l15;
    int r0  = kk * 32 + lhi * 8;
    const float* Wk = W + (size_t)k * C * C;
    bf16x8 o;
#pragma unroll
    for (int j = 0; j < 8; j++) o[j] = f2bf(Wk[(size_t)(r0 + j) * C + col]);
    ((bf16x8*)Wb)[tid] = o;
}

// ---------------- CSR build: histogram / scan / scatter ----------------
__global__ __launch_bounds__(256) void k_hist(const int* __restrict__ idx_out, int P,
                                              int* __restrict__ counts, int K) {
    int k = blockIdx.y, p = blockIdx.x * 256 + threadIdx.x;
    if (p >= P) return;
    int ov = idx_out[(size_t)k * P + p];
    atomicAdd(&counts[(ov >> 7) * K + k], 1);
}

__global__ __launch_bounds__(1024) void k_scan(int* __restrict__ counts,
                                               int* __restrict__ offsets,
                                               int* __restrict__ cursor, int nseg) {
    __shared__ int s[1024];
    const int tid = threadIdx.x;
    int running = 0;
    for (int base = 0; base < nseg; base += 1024) {
        int v = (base + tid < nseg) ? counts[base + tid] : 0;
        s[tid] = v;
        __syncthreads();
        for (int off = 1; off < 1024; off <<= 1) {
            int val = s[tid];
            if (tid >= off) val += s[tid - off];
            __syncthreads();
            s[tid] = val;
            __syncthreads();
        }
        int incl = s[tid];
        int total = s[1023];
        int excl = incl - v;
        if (base + tid < nseg) {
            offsets[base + tid] = running + excl;
            cursor[base + tid]  = running + excl;
        }
        running += total;
        __syncthreads();
    }
    if (tid == 0) offsets[nseg] = running;
}

__global__ __launch_bounds__(256) void k_scatter(const int* __restrict__ idx_in,
                                                 const int* __restrict__ idx_out, int P, int K,
                                                 int* __restrict__ cursor,
                                                 int* __restrict__ entries) {
    int k = blockIdx.y, p = blockIdx.x * 256 + threadIdx.x;
    if (p >= P) return;
    int ov = idx_out[(size_t)k * P + p];
    int iv = idx_in[(size_t)k * P + p];
    int seg = (ov >> 7) * K + k;
    int pos = atomicAdd(&cursor[seg], 1);
    entries[pos] = (iv << 7) | (ov & 127);
}

// ---------------- CSR sparse conv: per-output-tile block, f32 LDS accumulator, no global atomics ----
__global__ __launch_bounds__(256) void k_conv_csr(const short* __restrict__ feat,
                                                  const short* __restrict__ Wb,
                                                  const int* __restrict__ entries,
                                                  const int* __restrict__ offsets,
                                                  float* __restrict__ acc_out,
                                                  const float* __restrict__ residual,
                                                  int K, int n_out) {
    __shared__ float lacc[128 * LDSP];                 // 67.6 KB -> 2 blocks/CU
    const int tile = blockIdx.x;
    const int tidx = threadIdx.x;
    const int lane = tidx & 63, wave = tidx >> 6;
    const int l15 = lane & 15, lhi = lane >> 4;
    const int wcol0 = wave * 32;

    for (int i = tidx; i < 128 * LDSP; i += 256) lacc[i] = 0.f;
    __syncthreads();

    const f32x4 zero4 = {0.f, 0.f, 0.f, 0.f};
    for (int k = 0; k < K; k++) {
        const int seg = tile * K + k;
        const int s = offsets[seg], e = offsets[seg + 1];
        if (s >= e) continue;
        // W[k] fragments from frag-layout buffer: one 16B load each
        const bf16x8* wb = (const bf16x8*)(Wb + (size_t)k * 16384);
        bf16x8 bfr[2][4];
#pragma unroll
        for (int kk = 0; kk < 4; kk++)
#pragma unroll
            for (int n = 0; n < 2; n++)
                bfr[n][kk] = wb[((((kk * 4) + lhi) * 4 + wave) * 2 + n) * 16 + l15];

        // prologue: chunk c = s
        int c = s;
        int ei = c + l15; if (ei >= e) ei = e - 1;
        int ew = entries[ei];
        bf16x8 afr[4];
        {
            const bf16x8* rp = (const bf16x8*)(feat + (size_t)(ew >> 7) * C);
#pragma unroll
            for (int kk = 0; kk < 4; kk++) afr[kk] = rp[kk * 4 + lhi];
        }
        while (c < e) {
            const int cn = c + 16;
            // prefetch next chunk (entry + A frags) before compute/scatter
            int ewN = ew;
            bf16x8 afrN[4];
#pragma unroll
            for (int kk = 0; kk < 4; kk++) afrN[kk] = afr[kk];
            if (cn < e) {
                int ei2 = cn + l15; if (ei2 >= e) ei2 = e - 1;
                ewN = entries[ei2];
                const bf16x8* rpN = (const bf16x8*)(feat + (size_t)(ewN >> 7) * C);
#pragma unroll
                for (int kk = 0; kk < 4; kk++) afrN[kk] = rpN[kk * 4 + lhi];
            }
            f32x4 d0 = zero4, d1 = zero4;
#pragma unroll
            for (int kk = 0; kk < 4; kk++) {
                d0 = __builtin_amdgcn_mfma_f32_16x16x32_bf16(afr[kk], bfr[0][kk], d0, 0, 0, 0);
                d1 = __builtin_amdgcn_mfma_f32_16x16x32_bf16(afr[kk], bfr[1][kk], d1, 0, 0, 0);
            }
            const int nv = e - c;
#pragma unroll
            for (int r = 0; r < 4; r++) {
                const int rowi = lhi * 4 + r;
                const int ew2 = __shfl(ew, rowi, 64);
                if (rowi < nv) {
                    const int o7 = ew2 & 127;
                    atomicAdd(&lacc[o7 * LDSP + wcol0 + l15],      d0[r]);
                    atomicAdd(&lacc[o7 * LDSP + wcol0 + 16 + l15], d1[r]);
                }
            }
            ew = ewN;
#pragma unroll
            for (int kk = 0; kk < 4; kk++) afr[kk] = afrN[kk];
            c = cn;
        }
    }
    __syncthreads();

    // flush tile: plain coalesced stores (optionally + residual)
    const int rbase = tile * 128;
    const int rcnt = min(128, n_out - rbase);
    for (int r = wave; r < rcnt; r += 4) {
        const size_t go = (size_t)(rbase + r) * C + 2 * lane;
        float v0 = lacc[r * LDSP + 2 * lane];
        float v1 = lacc[r * LDSP + 2 * lane + 1];
        if (residual) { v0 += residual[go]; v1 += residual[go + 1]; }
        float2 o; o.x = v0; o.y = v1;
        *(float2*)(acc_out + go) = o;
    }
}

// ---------------- BN stats over f32 table: per-channel sum / sumsq of lrelu ----------------
__global__ __launch_bounds__(256) void k_stats(const float* __restrict__ x, int n,
                                               float* __restrict__ stats) {
    const int t  = threadIdx.x;
    const int c4 = (t & 31) * 4;
    const int rg = t >> 5;
    float s0 = 0, s1 = 0, s2 = 0, s3 = 0, q0 = 0, q1 = 0, q2 = 0, q3 = 0;
    for (int r = blockIdx.x * 8 + rg; r < n; r += gridDim.x * 8) {
        f32x4 v = *(const f32x4*)(x + (size_t)r * C + c4);
        float y0 = lrelu(v.x), y1 = lrelu(v.y), y2 = lrelu(v.z), y3 = lrelu(v.w);
        s0 += y0; s1 += y1; s2 += y2; s3 += y3;
        q0 += y0 * y0; q1 += y1 * y1; q2 += y2 * y2; q3 += y3 * y3;
    }
    __shared__ float rs[8][128];
    __shared__ float rq[8][128];
    rs[rg][c4] = s0; rs[rg][c4 + 1] = s1; rs[rg][c4 + 2] = s2; rs[rg][c4 + 3] = s3;
    rq[rg][c4] = q0; rq[rg][c4 + 1] = q1; rq[rg][c4 + 2] = q2; rq[rg][c4 + 3] = q3;
    __syncthreads();
    if (t < 128) {
        float S = 0, Q = 0;
#pragma unroll
        for (int g = 0; g < 8; g++) { S += rs[g][t]; Q += rq[g][t]; }
        unsafeAtomicAdd(&stats[t], S);
        unsafeAtomicAdd(&stats[128 + t], Q);
    }
}

// ---------------- apply LReLU + BN on f32 table; emit bf16 table and/or f32 ----------------
__global__ __launch_bounds__(256) void k_apply(const float* x, const float* __restrict__ stats,
                                               const float* __restrict__ g, const float* __restrict__ b,
                                               int n, float inv_n,
                                               short* __restrict__ out_bf, float* out_f) {
    __shared__ float sc[128], sh[128];
    const int t = threadIdx.x;
    if (t < 128) {
        float m = stats[t] * inv_n;
        float v = stats[128 + t] * inv_n - m * m;
        float s = rsqrtf(v + EPS) * g[t];
        sc[t] = s; sh[t] = b[t] - m * s;
    }
    __syncthreads();
    const int c4 = (t & 31) * 4;
    const int rg = t >> 5;
    const float s0 = sc[c4], s1 = sc[c4 + 1], s2 = sc[c4 + 2], s3 = sc[c4 + 3];
    const float h0 = sh[c4], h1 = sh[c4 + 1], h2 = sh[c4 + 2], h3 = sh[c4 + 3];
    for (int r = blockIdx.x * 8 + rg; r < n; r += gridDim.x * 8) {
        f32x4 v = *(const f32x4*)(x + (size_t)r * C + c4);
        f32x4 o;
        o.x = lrelu(v.x) * s0 + h0;
        o.y = lrelu(v.y) * s1 + h1;
        o.z = lrelu(v.z) * s2 + h2;
        o.w = lrelu(v.w) * s3 + h3;
        if (out_f) *(f32x4*)(out_f + (size_t)r * C + c4) = o;
        if (out_bf) {
            short4v ob;
            ob.x = f2bf(o.x); ob.y = f2bf(o.y); ob.z = f2bf(o.z); ob.w = f2bf(o.w);
            *(short4v*)(out_bf + (size_t)r * C + c4) = ob;
        }
    }
}

extern "C" void kernel_launch(void* const* d_in, const int* in_sizes, int n_in,
                              void* d_out, int out_size, void* d_ws, size_t ws_size,
                              hipStream_t stream) {
    const float* x_feat = (const float*)d_in[0];
    const float* skip   = (const float*)d_in[1];
    const float* W_t  = (const float*)d_in[2];
    const float* g_t  = (const float*)d_in[3];
    const float* b_t  = (const float*)d_in[4];
    const float* W_up = (const float*)d_in[5];
    const float* W1   = (const float*)d_in[6];
    const float* g1   = (const float*)d_in[7];
    const float* b1   = (const float*)d_in[8];
    const float* W2   = (const float*)d_in[9];
    const float* g2   = (const float*)d_in[10];
    const float* b2   = (const float*)d_in[11];
    const float* W3   = (const float*)d_in[12];
    const float* g3   = (const float*)d_in[13];
    const float* b3   = (const float*)d_in[14];
    const int* ti_in  = (const int*)d_in[15];
    const int* ti_out = (const int*)d_in[16];
    const int* ui_in  = (const int*)d_in[17];
    const int* ui_out = (const int*)d_in[18];
    const int* i1_in  = (const int*)d_in[19];
    const int* i1_out = (const int*)d_in[20];
    const int* i2_in  = (const int*)d_in[21];
    const int* i2_out = (const int*)d_in[22];
    const int* i3_in  = (const int*)d_in[23];
    const int* i3_out = (const int*)d_in[24];

    // Two 41MB regions. Each serves EITHER as a bf16 feature table OR as the CSR
    // scratch (entries / offsets / cursor / Wb) for the conv whose feats live in
    // the other region. Lifetimes alternate; footprint identical to round 3.
    char* regA = (char*)d_ws;
    char* regB = (char*)d_ws + 40960000;
    float* stats = (float*)((char*)d_ws + 81920000);   // 1 KB
    short* Atab = (short*)regA;
    short* Btab = (short*)regB;
    float* ACC  = (float*)d_out;                        // f32 accumulator / final output

    #define ENT(r)  ((int*)(r))                         // entries: <= 4,320,000 * 4B
    #define OFF(r)  ((int*)((r) + 17280000))            // offsets: <= 33751 * 4B
    #define CUR(r)  ((int*)((r) + 17420000))            // counts/cursor
    #define WBF(r)  ((short*)((r) + 17560000))          // Wb: <= 884,736 B

    const int T_IN  = (N_IN  + 127) / 128;              // 469
    const int T_OUT = (N_OUT + 127) / 128;              // 1250

    #define BUILD(reg, Wp, Kc, iin, iout, Pp, Tt)                                              \
        k_wconv<<<((Kc) * 2048 + 255) / 256, 256, 0, stream>>>(Wp, WBF(reg), Kc);              \
        hipMemsetAsync(CUR(reg), 0, (size_t)(Tt) * (Kc) * 4, stream);                          \
        k_hist<<<dim3(((Pp) + 255) / 256, Kc), 256, 0, stream>>>(iout, Pp, CUR(reg), Kc);      \
        k_scan<<<1, 1024, 0, stream>>>(CUR(reg), OFF(reg), CUR(reg), (Tt) * (Kc));             \
        k_scatter<<<dim3(((Pp) + 255) / 256, Kc), 256, 0, stream>>>(iin, iout, Pp, Kc,         \
                                                                    CUR(reg), ENT(reg))

    // ---- trans_dilao (27 taps, n_out=N_IN): feats=A(x), structs in regB ----
    k_f32_to_bf16<<<1024, 256, 0, stream>>>(x_feat, Atab, N_IN * C / 4);
    BUILD(regB, W_t, 27, ti_in, ti_out, N_IN, T_IN);
    k_conv_csr<<<T_IN, 256, 0, stream>>>(Atab, WBF(regB), ENT(regB), OFF(regB),
                                         ACC, nullptr, 27, N_IN);
    hipMemsetAsync(stats, 0, 1024, stream);
    k_stats<<<512, 256, 0, stream>>>(ACC, N_IN, stats);
    k_apply<<<512, 256, 0, stream>>>(ACC, stats, g_t, b_t, N_IN, 1.f / N_IN, Btab, nullptr);

    // ---- upsample (27 taps, n_out=N_OUT) + skip residual: feats=B, structs in regA ----
    BUILD(regA, W_up, 27, ui_in, ui_out, N_OUT, T_OUT);
    k_conv_csr<<<T_OUT, 256, 0, stream>>>(Btab, WBF(regA), ENT(regA), OFF(regA),
                                          ACC, skip, 27, N_OUT);
    k_f32_to_bf16<<<2048, 256, 0, stream>>>(ACC, Atab, N_OUT * C / 4);

    // ---- conv1 (9 taps): feats=A, structs in regB ----
    BUILD(regB, W1, 9, i1_in, i1_out, N_OUT, T_OUT);
    k_conv_csr<<<T_OUT, 256, 0, stream>>>(Atab, WBF(regB), ENT(regB), OFF(regB),
                                          ACC, nullptr, 9, N_OUT);
    hipMemsetAsync(stats, 0, 1024, stream);
    k_stats<<<512, 256, 0, stream>>>(ACC, N_OUT, stats);
    k_apply<<<512, 256, 0, stream>>>(ACC, stats, g1, b1, N_OUT, 1.f / N_OUT, Btab, nullptr);

    // ---- conv2 (9 taps): feats=B, structs in regA ----
    BUILD(regA, W2, 9, i2_in, i2_out, N_OUT, T_OUT);
    k_conv_csr<<<T_OUT, 256, 0, stream>>>(Btab, WBF(regA), ENT(regA), OFF(regA),
                                          ACC, nullptr, 9, N_OUT);
    hipMemsetAsync(stats, 0, 1024, stream);
    k_stats<<<512, 256, 0, stream>>>(ACC, N_OUT, stats);
    k_apply<<<512, 256, 0, stream>>>(ACC, stats, g2, b2, N_OUT, 1.f / N_OUT, Atab, nullptr);

    // ---- conv3 (27 taps): feats=A, structs in regB; final BN in place (f32) ----
    BUILD(regB, W3, 27, i3_in, i3_out, N_OUT, T_OUT);
    k_conv_csr<<<T_OUT, 256, 0, stream>>>(Atab, WBF(regB), ENT(regB), OFF(regB),
                                          ACC, nullptr, 27, N_OUT);
    hipMemsetAsync(stats, 0, 1024, stream);
    k_stats<<<512, 256, 0, stream>>>(ACC, N_OUT, stats);
    k_apply<<<512, 256, 0, stream>>>(ACC, stats, g3, b3, N_OUT, 1.f / N_OUT, nullptr, ACC);
}

// Round 7
// 10701.466 us; speedup vs baseline: 1.1391x; 1.1391x over previous
//
#include <hip/hip_runtime.h>
#include <hip/hip_bf16.h>

typedef __attribute__((ext_vector_type(8))) short bf16x8;      // 8 bf16 = 4 VGPRs (MFMA A/B frag)
typedef __attribute__((ext_vector_type(4))) short short4v;     // 4 bf16
typedef __attribute__((ext_vector_type(4))) float f32x4;       // MFMA C/D frag

#define N_IN  60000
#define N_OUT 160000
#define C     128
#define EPS   1e-3f
#define SLOPE 0.01f
#define LDSP  132    // LDS accumulator row pitch (dwords)
#define DEADF (1 << 30)

__device__ inline short f2bf(float f) {            // RNE f32 -> bf16
    unsigned u = __builtin_bit_cast(unsigned, f);
    u += 0x7FFFu + ((u >> 16) & 1u);
    return (short)(u >> 16);
}
__device__ inline float lrelu(float x) { return x > 0.f ? x : SLOPE * x; }

// ---------------- f32 -> bf16 convert ----------------
__global__ __launch_bounds__(256) void k_f32_to_bf16(const float* __restrict__ in,
                                                     short* __restrict__ out, int count4) {
    int i = blockIdx.x * 256 + threadIdx.x, stride = gridDim.x * 256;
    for (; i < count4; i += stride) {
        f32x4 v = ((const f32x4*)in)[i];
        short4v o;
        o.x = f2bf(v.x); o.y = f2bf(v.y); o.z = f2bf(v.z); o.w = f2bf(v.w);
        ((short4v*)out)[i] = o;
    }
}

// ---------------- W (f32 [K][128][128]) -> bf16 fragment-layout buffer ----------------
// fragid bits: [kk:2][lhi:2][w:2][n:1][l15:4]; element j = W[k][kk*32+lhi*8+j][w*32+n*16+l15]
__global__ __launch_bounds__(256) void k_wconv(const float* __restrict__ W,
                                               short* __restrict__ Wb, int K) {
    int tid = blockIdx.x * 256 + threadIdx.x;
    if (tid >= K * 2048) return;
    int idx = tid;
    int l15 = idx & 15;  idx >>= 4;
    int n   = idx & 1;   idx >>= 1;
    int w   = idx & 3;   idx >>= 2;
    int lhi = idx & 3;   idx >>= 2;
    int kk  = idx & 3;   idx >>= 2;
    int k   = idx;
    int col = w * 32 + n * 16 + l15;
    int r0  = kk * 32 + lhi * 8;
    const float* Wk = W + (size_t)k * C * C;
    bf16x8 o;
#pragma unroll
    for (int j = 0; j < 8; j++) o[j] = f2bf(Wk[(size_t)(r0 + j) * C + col]);
    ((bf16x8*)Wb)[tid] = o;
}

// ---------------- CSR build: histogram / padded scan / scatter / pad-fill ----------------
__global__ __launch_bounds__(256) void k_hist(const int* __restrict__ idx_out, int P,
                                              int* __restrict__ counts, int K) {
    int k = blockIdx.y, p = blockIdx.x * 256 + threadIdx.x;
    if (p >= P) return;
    int ov = idx_out[(size_t)k * P + p];
    atomicAdd(&counts[(ov >> 6) * K + k], 1);
}

// exclusive scan of ceil(count/16)*16; writes offsets[0..nseg] and cursor[0..nseg-1]
__global__ __launch_bounds__(1024) void k_scan(int* __restrict__ counts,
                                               int* __restrict__ offsets,
                                               int* __restrict__ cursor, int nseg) {
    __shared__ int wsum[16];
    __shared__ int s_carry;
    const int tid = threadIdx.x, lane = tid & 63, wid = tid >> 6;
    if (tid == 0) s_carry = 0;
    __syncthreads();
    for (int base = 0; base < nseg; base += 1024) {
        int i = base + tid;
        int raw = (i < nseg) ? counts[i] : 0;
        int v = (raw + 15) & ~15;
        int incl = v;
#pragma unroll
        for (int off = 1; off < 64; off <<= 1) {
            int u = __shfl_up(incl, off, 64);
            if (lane >= off) incl += u;
        }
        if (lane == 63) wsum[wid] = incl;
        __syncthreads();
        if (tid == 0) {
            int run = s_carry;
#pragma unroll
            for (int j = 0; j < 16; j++) { int t = wsum[j]; wsum[j] = run; run += t; }
            s_carry = run;
        }
        __syncthreads();
        int excl = wsum[wid] + incl - v;
        if (i < nseg) { offsets[i] = excl; cursor[i] = excl; }
        __syncthreads();
    }
    if (tid == 0) offsets[nseg] = s_carry;
}

__global__ __launch_bounds__(256) void k_scatter(const int* __restrict__ idx_in,
                                                 const int* __restrict__ idx_out, int P, int K,
                                                 int* __restrict__ cursor,
                                                 int* __restrict__ entries) {
    int k = blockIdx.y, p = blockIdx.x * 256 + threadIdx.x;
    if (p >= P) return;
    int ov = idx_out[(size_t)k * P + p];
    int iv = idx_in[(size_t)k * P + p];
    int seg = (ov >> 6) * K + k;
    int pos = atomicAdd(&cursor[seg], 1);
    entries[pos] = (iv << 6) | (ov & 63);
}

__global__ __launch_bounds__(64) void k_pad(const int* __restrict__ cursor,
                                            const int* __restrict__ offsets,
                                            int* __restrict__ entries) {
    int seg = blockIdx.x;
    for (int i = cursor[seg] + threadIdx.x; i < offsets[seg + 1]; i += 64)
        entries[i] = DEADF;
}

// ---------------- CSR sparse conv: 64-row tile, flattened padded chunk stream,
//                  depth-2 ping-pong pipeline, f32 LDS accumulator, no global atomics ----
__global__ __launch_bounds__(256, 4) void k_conv_csr(const short* __restrict__ feat,
                                                     const short* __restrict__ Wb,
                                                     const int* __restrict__ entries,
                                                     const int* __restrict__ offsets,
                                                     float* __restrict__ acc_out,
                                                     const float* __restrict__ residual,
                                                     int K, int n_out) {
    __shared__ float lacc[64 * LDSP];                 // 33.8 KB -> 4 blocks/CU
    const int tile = blockIdx.x;
    const int tidx = threadIdx.x;
    const int lane = tidx & 63, wave = tidx >> 6;
    const int l15 = lane & 15, lhi = lane >> 4;
    const int wcol0 = wave * 32;

    for (int i = tidx; i < 64 * LDSP; i += 256) lacc[i] = 0.f;

    const int segbase = tile * K;
    const int cblk = offsets[segbase];
    const int eblk = offsets[segbase + K];
    __syncthreads();

    if (cblk < eblk) {
        const f32x4 zero4 = {0.f, 0.f, 0.f, 0.f};
        int kk_idx = 0;
        int knext = offsets[segbase + 1];
        bf16x8 bfr[2][4];

        auto LOADB = [&](int k) {
            const bf16x8* wb = (const bf16x8*)(Wb + (size_t)k * 16384);
#pragma unroll
            for (int kk = 0; kk < 4; kk++)
#pragma unroll
                for (int n = 0; n < 2; n++)
                    bfr[n][kk] = wb[((((kk * 4) + lhi) * 4 + wave) * 2 + n) * 16 + l15];
        };
        auto GATHER = [&](bf16x8 (&afr)[4], int ew) {
            const bf16x8* rp = (const bf16x8*)(feat + (size_t)((ew >> 6) & 0x3FFFF) * C);
#pragma unroll
            for (int kk = 0; kk < 4; kk++) afr[kk] = rp[kk * 4 + lhi];
        };
        auto COMPUTE = [&](bf16x8 (&afr)[4], int sc, int cpos) {
            while (cpos >= knext) {            // uniform scalar k-boundary walk
                ++kk_idx;
                knext = offsets[segbase + kk_idx + 1];
                LOADB(kk_idx);
            }
            f32x4 d0 = zero4, d1 = zero4;
#pragma unroll
            for (int kk = 0; kk < 4; kk++) {
                d0 = __builtin_amdgcn_mfma_f32_16x16x32_bf16(afr[kk], bfr[0][kk], d0, 0, 0, 0);
                d1 = __builtin_amdgcn_mfma_f32_16x16x32_bf16(afr[kk], bfr[1][kk], d1, 0, 0, 0);
            }
#pragma unroll
            for (int r = 0; r < 4; r++) {
                const int rowi = lhi * 4 + r;
                const int s2 = __shfl(sc, rowi, 64);
                if (!(s2 & DEADF)) {
                    const int o6 = s2 & 63;
                    atomicAdd(&lacc[o6 * LDSP + wcol0 + l15],      d0[r]);
                    atomicAdd(&lacc[o6 * LDSP + wcol0 + 16 + l15], d1[r]);
                }
            }
        };

        LOADB(0);
        int c = cblk;
        const int elast = eblk - 1;
        int ewA = entries[min(c + l15,      elast)];
        int ewB = entries[min(c + 16 + l15, elast)];
        int scA = ewA, scB = ewB;
        bf16x8 afrA[4], afrB[4];
        GATHER(afrA, ewA);
        GATHER(afrB, ewB);
        ewA = entries[min(c + 32 + l15, elast)];
        ewB = entries[min(c + 48 + l15, elast)];

        while (c < eblk) {
            COMPUTE(afrA, scA, c);
            scA = ewA;
            GATHER(afrA, ewA);                         // rows for chunk c+32
            ewA = entries[min(c + 64 + l15, elast)];   // entries for chunk c+64
            if (c + 16 < eblk) {
                COMPUTE(afrB, scB, c + 16);
                scB = ewB;
                GATHER(afrB, ewB);
                ewB = entries[min(c + 80 + l15, elast)];
            }
            c += 32;
        }
    }
    __syncthreads();

    // flush tile: plain coalesced stores (optionally + residual)
    const int rbase = tile * 64;
    const int rcnt = min(64, n_out - rbase);
    for (int rr = wave; rr < rcnt; rr += 4) {
        const size_t go = (size_t)(rbase + rr) * C + 2 * lane;
        float v0 = lacc[rr * LDSP + 2 * lane];
        float v1 = lacc[rr * LDSP + 2 * lane + 1];
        if (residual) { v0 += residual[go]; v1 += residual[go + 1]; }
        float2 o; o.x = v0; o.y = v1;
        *(float2*)(acc_out + go) = o;
    }
}

// ---------------- BN stats over f32 table: per-channel sum / sumsq of lrelu ----------------
__global__ __launch_bounds__(256) void k_stats(const float* __restrict__ x, int n,
                                               float* __restrict__ stats) {
    const int t  = threadIdx.x;
    const int c4 = (t & 31) * 4;
    const int rg = t >> 5;
    float s0 = 0, s1 = 0, s2 = 0, s3 = 0, q0 = 0, q1 = 0, q2 = 0, q3 = 0;
    for (int r = blockIdx.x * 8 + rg; r < n; r += gridDim.x * 8) {
        f32x4 v = *(const f32x4*)(x + (size_t)r * C + c4);
        float y0 = lrelu(v.x), y1 = lrelu(v.y), y2 = lrelu(v.z), y3 = lrelu(v.w);
        s0 += y0; s1 += y1; s2 += y2; s3 += y3;
        q0 += y0 * y0; q1 += y1 * y1; q2 += y2 * y2; q3 += y3 * y3;
    }
    __shared__ float rs[8][128];
    __shared__ float rq[8][128];
    rs[rg][c4] = s0; rs[rg][c4 + 1] = s1; rs[rg][c4 + 2] = s2; rs[rg][c4 + 3] = s3;
    rq[rg][c4] = q0; rq[rg][c4 + 1] = q1; rq[rg][c4 + 2] = q2; rq[rg][c4 + 3] = q3;
    __syncthreads();
    if (t < 128) {
        float S = 0, Q = 0;
#pragma unroll
        for (int g = 0; g < 8; g++) { S += rs[g][t]; Q += rq[g][t]; }
        unsafeAtomicAdd(&stats[t], S);
        unsafeAtomicAdd(&stats[128 + t], Q);
    }
}

// ---------------- apply LReLU + BN on f32 table; emit bf16 table and/or f32 ----------------
__global__ __launch_bounds__(256) void k_apply(const float* x, const float* __restrict__ stats,
                                               const float* __restrict__ g, const float* __restrict__ b,
                                               int n, float inv_n,
                                               short* __restrict__ out_bf, float* out_f) {
    __shared__ float sc[128], sh[128];
    const int t = threadIdx.x;
    if (t < 128) {
        float m = stats[t] * inv_n;
        float v = stats[128 + t] * inv_n - m * m;
        float s = rsqrtf(v + EPS) * g[t];
        sc[t] = s; sh[t] = b[t] - m * s;
    }
    __syncthreads();
    const int c4 = (t & 31) * 4;
    const int rg = t >> 5;
    const float s0 = sc[c4], s1 = sc[c4 + 1], s2 = sc[c4 + 2], s3 = sc[c4 + 3];
    const float h0 = sh[c4], h1 = sh[c4 + 1], h2 = sh[c4 + 2], h3 = sh[c4 + 3];
    for (int r = blockIdx.x * 8 + rg; r < n; r += gridDim.x * 8) {
        f32x4 v = *(const f32x4*)(x + (size_t)r * C + c4);
        f32x4 o;
        o.x = lrelu(v.x) * s0 + h0;
        o.y = lrelu(v.y) * s1 + h1;
        o.z = lrelu(v.z) * s2 + h2;
        o.w = lrelu(v.w) * s3 + h3;
        if (out_f) *(f32x4*)(out_f + (size_t)r * C + c4) = o;
        if (out_bf) {
            short4v ob;
            ob.x = f2bf(o.x); ob.y = f2bf(o.y); ob.z = f2bf(o.z); ob.w = f2bf(o.w);
            *(short4v*)(out_bf + (size_t)r * C + c4) = ob;
        }
    }
}

extern "C" void kernel_launch(void* const* d_in, const int* in_sizes, int n_in,
                              void* d_out, int out_size, void* d_ws, size_t ws_size,
                              hipStream_t stream) {
    const float* x_feat = (const float*)d_in[0];
    const float* skip   = (const float*)d_in[1];
    const float* W_t  = (const float*)d_in[2];
    const float* g_t  = (const float*)d_in[3];
    const float* b_t  = (const float*)d_in[4];
    const float* W_up = (const float*)d_in[5];
    const float* W1   = (const float*)d_in[6];
    const float* g1   = (const float*)d_in[7];
    const float* b1   = (const float*)d_in[8];
    const float* W2   = (const float*)d_in[9];
    const float* g2   = (const float*)d_in[10];
    const float* b2   = (const float*)d_in[11];
    const float* W3   = (const float*)d_in[12];
    const float* g3   = (const float*)d_in[13];
    const float* b3   = (const float*)d_in[14];
    const int* ti_in  = (const int*)d_in[15];
    const int* ti_out = (const int*)d_in[16];
    const int* ui_in  = (const int*)d_in[17];
    const int* ui_out = (const int*)d_in[18];
    const int* i1_in  = (const int*)d_in[19];
    const int* i1_out = (const int*)d_in[20];
    const int* i2_in  = (const int*)d_in[21];
    const int* i2_out = (const int*)d_in[22];
    const int* i3_in  = (const int*)d_in[23];
    const int* i3_out = (const int*)d_in[24];

    // Two 41MB regions: bf16 feature table OR CSR scratch for the conv whose
    // feats live in the other region. Lifetimes alternate.
    char* regA = (char*)d_ws;
    char* regB = (char*)d_ws + 40960000;
    float* stats = (float*)((char*)d_ws + 81920000);   // 1 KB
    short* Atab = (short*)regA;
    short* Btab = (short*)regB;
    float* ACC  = (float*)d_out;                        // f32 accumulator / final output

    #define ENT(r)  ((int*)(r))                         // padded entries: <= 5.4M * 4B
    #define OFF(r)  ((int*)((r) + 22000000))            // offsets: <= 67501 * 4B
    #define CUR(r)  ((int*)((r) + 22400000))            // counts/cursor
    #define WBF(r)  ((short*)((r) + 22800000))          // Wb: <= 884,736 B

    const int T_IN  = (N_IN  + 63) / 64;                // 938
    const int T_OUT = (N_OUT + 63) / 64;                // 2500

    #define BUILD(reg, Wp, Kc, iin, iout, Pp, Tt)                                              \
        k_wconv<<<((Kc) * 2048 + 255) / 256, 256, 0, stream>>>(Wp, WBF(reg), Kc);              \
        hipMemsetAsync(CUR(reg), 0, (size_t)(Tt) * (Kc) * 4, stream);                          \
        k_hist<<<dim3(((Pp) + 255) / 256, Kc), 256, 0, stream>>>(iout, Pp, CUR(reg), Kc);      \
        k_scan<<<1, 1024, 0, stream>>>(CUR(reg), OFF(reg), CUR(reg), (Tt) * (Kc));             \
        k_scatter<<<dim3(((Pp) + 255) / 256, Kc), 256, 0, stream>>>(iin, iout, Pp, Kc,         \
                                                                    CUR(reg), ENT(reg));       \
        k_pad<<<(Tt) * (Kc), 64, 0, stream>>>(CUR(reg), OFF(reg), ENT(reg))

    // ---- trans_dilao (27 taps, n_out=N_IN): feats=A(x), structs in regB ----
    k_f32_to_bf16<<<1024, 256, 0, stream>>>(x_feat, Atab, N_IN * C / 4);
    BUILD(regB, W_t, 27, ti_in, ti_out, N_IN, T_IN);
    k_conv_csr<<<T_IN, 256, 0, stream>>>(Atab, WBF(regB), ENT(regB), OFF(regB),
                                         ACC, nullptr, 27, N_IN);
    hipMemsetAsync(stats, 0, 1024, stream);
    k_stats<<<512, 256, 0, stream>>>(ACC, N_IN, stats);
    k_apply<<<512, 256, 0, stream>>>(ACC, stats, g_t, b_t, N_IN, 1.f / N_IN, Btab, nullptr);

    // ---- upsample (27 taps, n_out=N_OUT) + skip residual: feats=B, structs in regA ----
    BUILD(regA, W_up, 27, ui_in, ui_out, N_OUT, T_OUT);
    k_conv_csr<<<T_OUT, 256, 0, stream>>>(Btab, WBF(regA), ENT(regA), OFF(regA),
                                          ACC, skip, 27, N_OUT);
    k_f32_to_bf16<<<2048, 256, 0, stream>>>(ACC, Atab, N_OUT * C / 4);

    // ---- conv1 (9 taps): feats=A, structs in regB ----
    BUILD(regB, W1, 9, i1_in, i1_out, N_OUT, T_OUT);
    k_conv_csr<<<T_OUT, 256, 0, stream>>>(Atab, WBF(regB), ENT(regB), OFF(regB),
                                          ACC, nullptr, 9, N_OUT);
    hipMemsetAsync(stats, 0, 1024, stream);
    k_stats<<<512, 256, 0, stream>>>(ACC, N_OUT, stats);
    k_apply<<<512, 256, 0, stream>>>(ACC, stats, g1, b1, N_OUT, 1.f / N_OUT, Btab, nullptr);

    // ---- conv2 (9 taps): feats=B, structs in regA ----
    BUILD(regA, W2, 9, i2_in, i2_out, N_OUT, T_OUT);
    k_conv_csr<<<T_OUT, 256, 0, stream>>>(Btab, WBF(regA), ENT(regA), OFF(regA),
                                          ACC, nullptr, 9, N_OUT);
    hipMemsetAsync(stats, 0, 1024, stream);
    k_stats<<<512, 256, 0, stream>>>(ACC, N_OUT, stats);
    k_apply<<<512, 256, 0, stream>>>(ACC, stats, g2, b2, N_OUT, 1.f / N_OUT, Atab, nullptr);

    // ---- conv3 (27 taps): feats=A, structs in regB; final BN in place (f32) ----
    BUILD(regB, W3, 27, i3_in, i3_out, N_OUT, T_OUT);
    k_conv_csr<<<T_OUT, 256, 0, stream>>>(Atab, WBF(regB), ENT(regB), OFF(regB),
                                          ACC, nullptr, 27, N_OUT);
    hipMemsetAsync(stats, 0, 1024, stream);
    k_stats<<<512, 256, 0, stream>>>(ACC, N_OUT, stats);
    k_apply<<<512, 256, 0, stream>>>(ACC, stats, g3, b3, N_OUT, 1.f / N_OUT, nullptr, ACC);
}